// Round 7
// baseline (30010.510 us; speedup 1.0000x reference)
//
#include <hip/hip_runtime.h>

#define NRES 2048
#define NBLK 256
#define RBUF 4   // rotation depth; max inter-block skew is 1 step -> >=3 race-free
#define NXCD 8
#define MIR_SPINS 16  // bounded mirror spin before vtag fallback

typedef unsigned long long u64;
typedef unsigned int u32;

// ---------------- W transpose: Wt[j][i] = W[i][j] ----------------
__global__ __launch_bounds__(256) void transpose_k(const float* __restrict__ W,
                                                   float* __restrict__ Wt) {
  __shared__ float tile[32][33];
  const int tx = threadIdx.x, ty = threadIdx.y;
  const int x = blockIdx.x * 32 + tx;
  const int y0 = blockIdx.y * 32;
#pragma unroll
  for (int j = ty; j < 32; j += 8)
    tile[j][tx] = W[(size_t)(y0 + j) * NRES + x];
  __syncthreads();
  const int x2 = blockIdx.y * 32 + tx;
  const int y2 = blockIdx.x * 32;
#pragma unroll
  for (int j = ty; j < 32; j += 8)
    Wt[(size_t)(y2 + j) * NRES + x2] = tile[tx][j];
}

// ---------------- uproj GEMM: U[M,N] = X[M,K] @ B[K,N], fp32 ----------------
__global__ __launch_bounds__(256) void gemm_uproj(const float* __restrict__ X,
                                                  const float* __restrict__ B,
                                                  float* __restrict__ U,
                                                  int M, int N, int K) {
  __shared__ float As[16][128];  // As[k][m]
  __shared__ float Bs[16][128];  // Bs[k][n]
  const int tid = threadIdx.x;
  const int tx = tid & 15, ty = tid >> 4;
  const int m0 = blockIdx.y * 128, n0 = blockIdx.x * 128;

  float acc[8][8];
#pragma unroll
  for (int i = 0; i < 8; i++)
#pragma unroll
    for (int j = 0; j < 8; j++) acc[i][j] = 0.f;

  const int sam = tid >> 1, sak = (tid & 1) * 8;   // A staging: row, k-half
  const int sbk = tid >> 4, sbn = (tid & 15) * 8;  // B staging: k, n-start

  for (int k0 = 0; k0 < K; k0 += 16) {
    const float* ap = X + (size_t)(m0 + sam) * K + k0 + sak;
    float4 a0 = *(const float4*)(ap);
    float4 a1 = *(const float4*)(ap + 4);
    As[sak + 0][sam] = a0.x; As[sak + 1][sam] = a0.y;
    As[sak + 2][sam] = a0.z; As[sak + 3][sam] = a0.w;
    As[sak + 4][sam] = a1.x; As[sak + 5][sam] = a1.y;
    As[sak + 6][sam] = a1.z; As[sak + 7][sam] = a1.w;
    const float* bp = B + (size_t)(k0 + sbk) * N + n0 + sbn;
    *(float4*)&Bs[sbk][sbn]     = *(const float4*)(bp);
    *(float4*)&Bs[sbk][sbn + 4] = *(const float4*)(bp + 4);
    __syncthreads();
#pragma unroll
    for (int kk = 0; kk < 16; kk++) {
      float a[8], b[8];
      *(float4*)&a[0] = *(const float4*)&As[kk][ty * 8];
      *(float4*)&a[4] = *(const float4*)&As[kk][ty * 8 + 4];
      *(float4*)&b[0] = *(const float4*)&Bs[kk][tx * 8];
      *(float4*)&b[4] = *(const float4*)&Bs[kk][tx * 8 + 4];
#pragma unroll
      for (int i = 0; i < 8; i++)
#pragma unroll
        for (int j = 0; j < 8; j++) acc[i][j] += a[i] * b[j];
    }
    __syncthreads();
  }
#pragma unroll
  for (int i = 0; i < 8; i++) {
    float* dst = U + (size_t)(m0 + ty * 8 + i) * N + n0 + tx * 8;
    *(float4*)dst       = *(float4*)&acc[i][0];
    *(float4*)(dst + 4) = *(float4*)&acc[i][4];
  }
}

// ---------------- persistent ESN scan, XCD-relay + bounded fallback ----------
// 256 blocks x 256 threads, cooperative. Block b owns columns [8b, 8b+8).
// Producers publish {tag=t+1, f32} words to vtag (L3) via atomic swap.
// One relay block per XCD (tid0 reads XCC_ID, atomic claim, LDS broadcast)
// polls vtag with agent loads and forwards arrivals into its XCD's mirror
// with PLAIN stores (CDNA L1 is write-through -> they land in the XCD-shared
// L2; the in-word tag makes ordering irrelevant). Consumers poll the mirror
// with sc0 loads (L1-bypass, L2-hit) for at most MIR_SPINS rounds, then
// FALL BACK to polling vtag directly (the proven R2-R4 loop) for the
// remaining words. All consumer waits are bounded; the only unbounded loop
// is the relay's vtag poll, which terminates because every block always
// publishes (consumers can't be blocked by a dead mirror). Stale mirror
// content across replays is harmless: tags exact-match t, and the
// trajectory is deterministic, so an improbable surviving (slot,tag) hit
// would carry the bit-identical value.
__global__ __launch_bounds__(256, 1) void esn_scan(const float* __restrict__ Wt,
                                                   const float* __restrict__ W,
                                                   u64* vtag,
                                                   u64* mirror,   // [NXCD][RBUF][NRES]
                                                   u32* xcd_cnt,  // 16-u32 spaced
                                                   float* __restrict__ UY,
                                                   int T, int relay_on) {
  __shared__ float v_lds[2][NRES];
  __shared__ int sh_relay, sh_xcd;
  const int b = blockIdx.x;
  const int tid = threadIdx.x;
  const int wv = tid >> 6;
  const int lane = tid & 63;
  const int h = lane >> 5;
  const int s = lane & 31;
  const int j = b * 8 + wv * 2 + h;

  if (tid == 0) {
    u32 xcc;
    asm volatile("s_getreg_b32 %0, hwreg(HW_REG_XCC_ID)" : "=s"(xcc));
    const int mx = (int)(xcc & (NXCD - 1));
    sh_xcd = mx;
    int rank = relay_on ? (int)atomicAdd(&xcd_cnt[mx * 16], 1u) : 1;
    sh_relay = (relay_on && rank == 0) ? 1 : 0;
  }

  // one-time: load column j of W into registers (coalesced via Wt)
  float2 w2[32];
  if (Wt) {
    const float2* wrow = (const float2*)(Wt + (size_t)j * NRES);
#pragma unroll
    for (int k = 0; k < 32; ++k) w2[k] = wrow[s + 32 * k];
  } else {
#pragma unroll
    for (int k = 0; k < 32; ++k) {
      w2[k].x = W[(size_t)(2 * s + 64 * k) * NRES + j];
      w2[k].y = W[(size_t)(2 * s + 64 * k + 1) * NRES + j];
    }
  }

  float vold = 0.f;  // v_{t-1}[j], live on s==0 lanes only
#pragma unroll
  for (int q = 0; q < 8; ++q) v_lds[0][tid + 256 * q] = 0.f;
  __syncthreads();  // publishes sh_relay / sh_xcd
  const int myxcd = sh_xcd;
  const bool polls_global = (sh_relay != 0) || !relay_on;

  for (int t = 0; t < T; ++t) {
    const int buf = t & 1;
    const size_t idx = (size_t)t * NRES + j;
    float u = (s == 0) ? UY[idx] : 0.f;  // in flight during the poll

    if (t > 0) {
      const int slot = (t - 1) & (RBUF - 1);
      u64* src = vtag + (size_t)slot * NRES;
      unsigned done = 0;
      if (polls_global) {
        // relay (or no-relay fallback): poll vtag in L3, forward to mirror
        u64* mir = mirror + ((size_t)myxcd * RBUF + slot) * NRES;
        while (done != 0xFFu) {
          u64 w[8];
#pragma unroll
          for (int q = 0; q < 8; ++q)
            w[q] = __hip_atomic_load(&src[tid + 256 * q], __ATOMIC_RELAXED,
                                     __HIP_MEMORY_SCOPE_AGENT);
#pragma unroll
          for (int q = 0; q < 8; ++q) {
            if (!(done & (1u << q)) && (u32)(w[q] >> 32) == (u32)t) {
              if (relay_on) mir[tid + 256 * q] = w[q];  // write-through -> XCD L2
              v_lds[buf][tid + 256 * q] = __uint_as_float((u32)w[q]);
              done |= 1u << q;
            }
          }
        }
      } else {
        // consumer: bounded poll of XCD-local mirror (sc0: L1-bypass, L2-hit)
        const u64 mb =
            (u64)(mirror + ((size_t)myxcd * RBUF + slot) * NRES) + (u64)tid * 8u;
        for (int spin = 0; done != 0xFFu && spin < MIR_SPINS; ++spin) {
          u64 w0, w1, w2_, w3, w4, w5, w6, w7;
          asm volatile(
              "global_load_dwordx2 %0, %8, off sc0\n\t"
              "global_load_dwordx2 %1, %9, off sc0\n\t"
              "global_load_dwordx2 %2, %10, off sc0\n\t"
              "global_load_dwordx2 %3, %11, off sc0\n\t"
              "global_load_dwordx2 %4, %12, off sc0\n\t"
              "global_load_dwordx2 %5, %13, off sc0\n\t"
              "global_load_dwordx2 %6, %14, off sc0\n\t"
              "global_load_dwordx2 %7, %15, off sc0\n\t"
              "s_waitcnt vmcnt(0)"
              : "=&v"(w0), "=&v"(w1), "=&v"(w2_), "=&v"(w3),
                "=&v"(w4), "=&v"(w5), "=&v"(w6), "=&v"(w7)
              : "v"(mb + 0 * 2048u), "v"(mb + 1 * 2048u),
                "v"(mb + 2 * 2048u), "v"(mb + 3 * 2048u),
                "v"(mb + 4 * 2048u), "v"(mb + 5 * 2048u),
                "v"(mb + 6 * 2048u), "v"(mb + 7 * 2048u)
              : "memory");
#define ESN_CHK(q, wq)                                              \
          if (!(done & (1u << q)) && (u32)((wq) >> 32) == (u32)t) { \
            v_lds[buf][tid + 256 * q] = __uint_as_float((u32)(wq)); \
            done |= 1u << q;                                        \
          }
          ESN_CHK(0, w0) ESN_CHK(1, w1) ESN_CHK(2, w2_) ESN_CHK(3, w3)
          ESN_CHK(4, w4) ESN_CHK(5, w5) ESN_CHK(6, w6) ESN_CHK(7, w7)
#undef ESN_CHK
        }
        // fallback: finish any stragglers against vtag (always terminates)
        while (done != 0xFFu) {
          u64 w[8];
#pragma unroll
          for (int q = 0; q < 8; ++q)
            w[q] = __hip_atomic_load(&src[tid + 256 * q], __ATOMIC_RELAXED,
                                     __HIP_MEMORY_SCOPE_AGENT);
#pragma unroll
          for (int q = 0; q < 8; ++q) {
            if (!(done & (1u << q)) && (u32)(w[q] >> 32) == (u32)t) {
              v_lds[buf][tid + 256 * q] = __uint_as_float((u32)w[q]);
              done |= 1u << q;
            }
          }
        }
      }
      __syncthreads();
    }

    // dot(v, W[:,j]) : 32 x float2, 2-way LDS aliasing (free), 2 acc chains
    float acc0 = 0.f, acc1 = 0.f;
#pragma unroll
    for (int k = 0; k < 32; k += 2) {
      float2 va = *(const float2*)&v_lds[buf][2 * s + 64 * k];
      float2 vb = *(const float2*)&v_lds[buf][2 * s + 64 * (k + 1)];
      acc0 += w2[k].x * va.x + w2[k].y * va.y;
      acc1 += w2[k + 1].x * vb.x + w2[k + 1].y * vb.y;
    }
    float acc = acc0 + acc1;
#pragma unroll
    for (int off = 16; off >= 1; off >>= 1) acc += __shfl_xor(acc, off);

    if (s == 0) {
      float xx = acc + u;
      float e = __expf(2.f * xx);        // v_exp_f32 path
      float th = 1.f - 2.f / (e + 1.f);  // == tanh(xx) exactly
      float vnew = 0.5f * vold + 0.5f * th;
      vold = vnew;
      UY[idx] = vnew;  // states[t][j]
      u64 w = ((u64)(u32)(t + 1) << 32) | (u64)__float_as_uint(vnew);
      (void)__hip_atomic_exchange(&vtag[(size_t)(t & (RBUF - 1)) * NRES + j],
                                  w, __ATOMIC_RELAXED,
                                  __HIP_MEMORY_SCOPE_AGENT);
    }
  }
}

extern "C" void kernel_launch(void* const* d_in, const int* in_sizes, int n_in,
                              void* d_out, int out_size, void* d_ws, size_t ws_size,
                              hipStream_t stream) {
  const float* x   = (const float*)d_in[0];
  const float* Win = (const float*)d_in[1];
  const float* W   = (const float*)d_in[2];
  float* U = (float*)d_out;

  const int T = out_size / NRES;  // 4096
  const int K = in_sizes[0] / T;  // 4096 (nInput)

  char* ws = (char*)d_ws;
  u64* vtag    = (u64*)ws;                 // [RBUF][NRES]    = 64 KB @ 0
  u32* xcd_cnt = (u32*)(ws + (64 << 10));  //                 @ 64 KB
  u64* mirror  = (u64*)(ws + (128 << 10)); // [8][RBUF][NRES] = 512 KB @ 128 KB
  int relay_on = ws_size >= (640u << 10) ? 1 : 0;
  float* Wt = nullptr;
  if (ws_size >= (1u << 20) + (size_t)NRES * NRES * sizeof(float))
    Wt = (float*)(ws + (1u << 20));        // 16 MB @ 1 MB

  // zero tags/counters/mirrors every launch (exact-match tags + zero = inert)
  hipMemsetAsync(ws, 0, relay_on ? (640u << 10) : (68u << 10), stream);

  if (Wt) transpose_k<<<dim3(NRES / 32, NRES / 32), dim3(32, 8), 0, stream>>>(W, Wt);

  gemm_uproj<<<dim3(NRES / 128, T / 128), 256, 0, stream>>>(x, Win, U, T, NRES, K);

  void* args[] = {(void*)&Wt, (void*)&W, (void*)&vtag, (void*)&mirror,
                  (void*)&xcd_cnt, (void*)&U, (void*)&T, (void*)&relay_on};
  hipLaunchCooperativeKernel((const void*)esn_scan, dim3(NBLK), dim3(256), args,
                             0, stream);
}

// Round 8
// 18079.648 us; speedup vs baseline: 1.6599x; 1.6599x over previous
//
#include <hip/hip_runtime.h>

#define NRES 2048
#define NBLK 256
#define RBUF 4  // rotation depth; max inter-block skew is 1 step -> >=3 race-free

typedef unsigned long long u64;
typedef unsigned int u32;

// ---------------- W transpose: Wt[j][i] = W[i][j] ----------------
__global__ __launch_bounds__(256) void transpose_k(const float* __restrict__ W,
                                                   float* __restrict__ Wt) {
  __shared__ float tile[32][33];
  const int tx = threadIdx.x, ty = threadIdx.y;
  const int x = blockIdx.x * 32 + tx;
  const int y0 = blockIdx.y * 32;
#pragma unroll
  for (int j = ty; j < 32; j += 8)
    tile[j][tx] = W[(size_t)(y0 + j) * NRES + x];
  __syncthreads();
  const int x2 = blockIdx.y * 32 + tx;
  const int y2 = blockIdx.x * 32;
#pragma unroll
  for (int j = ty; j < 32; j += 8)
    Wt[(size_t)(y2 + j) * NRES + x2] = tile[tx][j];
}

// ---------------- uproj GEMM: U[M,N] = X[M,K] @ B[K,N], fp32 ----------------
__global__ __launch_bounds__(256) void gemm_uproj(const float* __restrict__ X,
                                                  const float* __restrict__ B,
                                                  float* __restrict__ U,
                                                  int M, int N, int K) {
  __shared__ float As[16][128];  // As[k][m]
  __shared__ float Bs[16][128];  // Bs[k][n]
  const int tid = threadIdx.x;
  const int tx = tid & 15, ty = tid >> 4;
  const int m0 = blockIdx.y * 128, n0 = blockIdx.x * 128;

  float acc[8][8];
#pragma unroll
  for (int i = 0; i < 8; i++)
#pragma unroll
    for (int j = 0; j < 8; j++) acc[i][j] = 0.f;

  const int sam = tid >> 1, sak = (tid & 1) * 8;   // A staging: row, k-half
  const int sbk = tid >> 4, sbn = (tid & 15) * 8;  // B staging: k, n-start

  for (int k0 = 0; k0 < K; k0 += 16) {
    const float* ap = X + (size_t)(m0 + sam) * K + k0 + sak;
    float4 a0 = *(const float4*)(ap);
    float4 a1 = *(const float4*)(ap + 4);
    As[sak + 0][sam] = a0.x; As[sak + 1][sam] = a0.y;
    As[sak + 2][sam] = a0.z; As[sak + 3][sam] = a0.w;
    As[sak + 4][sam] = a1.x; As[sak + 5][sam] = a1.y;
    As[sak + 6][sam] = a1.z; As[sak + 7][sam] = a1.w;
    const float* bp = B + (size_t)(k0 + sbk) * N + n0 + sbn;
    *(float4*)&Bs[sbk][sbn]     = *(const float4*)(bp);
    *(float4*)&Bs[sbk][sbn + 4] = *(const float4*)(bp + 4);
    __syncthreads();
#pragma unroll
    for (int kk = 0; kk < 16; kk++) {
      float a[8], b[8];
      *(float4*)&a[0] = *(const float4*)&As[kk][ty * 8];
      *(float4*)&a[4] = *(const float4*)&As[kk][ty * 8 + 4];
      *(float4*)&b[0] = *(const float4*)&Bs[kk][tx * 8];
      *(float4*)&b[4] = *(const float4*)&Bs[kk][tx * 8 + 4];
#pragma unroll
      for (int i = 0; i < 8; i++)
#pragma unroll
        for (int j = 0; j < 8; j++) acc[i][j] += a[i] * b[j];
    }
    __syncthreads();
  }
#pragma unroll
  for (int i = 0; i < 8; i++) {
    float* dst = U + (size_t)(m0 + ty * 8 + i) * N + n0 + tx * 8;
    *(float4*)dst       = *(float4*)&acc[i][0];
    *(float4*)(dst + 4) = *(float4*)&acc[i][4];
  }
}

// ---------------- persistent ESN scan, tagged-value sync (512 thr) ---------
// 256 blocks x 512 threads (8 waves), cooperative, 1 block/CU. Block b owns
// columns [8b, 8b+8): ONE WAVE per column j = 8b + wv. Lane l holds W[:,j]
// rows {2l+128k, 2l+128k+1}, k=0..15 (32 floats = 16 float2 in VGPRs).
//
// Sync: v_t[j] published as one 64-bit word {tag=t+1, f32 bits} via
// fire-and-forget agent atomic swap (commits at the coherence point).
// Consumers poll the words branch-free: 4 words/thread/round (512 threads
// sweep all 2048), all loads in flight per round -> short rounds, small
// per-round tail. v_lds double-buffered: ONE barrier per step (a thread
// filling buf t&1 passed its step-(t-1) barrier, which happens-after all
// step-(t-2) reads of that buffer). v_old[j] stays in a register on the
// publishing lane. tanh via exact identity 1 - 2/(e^2x + 1) (v_exp_f32).
// Rationale (R7 post-mortem): the slowest of 256 blocks gates every step;
// halving each block's serial chain (poll round, LDS fill, dot, fill count)
// shrinks both the mean and the variance of that max.
__global__ __launch_bounds__(512, 1) void esn_scan(const float* __restrict__ Wt,
                                                   const float* __restrict__ W,
                                                   u64* vtag,
                                                   float* __restrict__ UY,
                                                   int T) {
  __shared__ float v_lds[2][NRES];
  const int b = blockIdx.x;
  const int tid = threadIdx.x;
  const int wv = tid >> 6;   // wave id 0..7 -> column
  const int lane = tid & 63;
  const int j = b * 8 + wv;

  // one-time: load column j of W into registers (coalesced via Wt)
  float2 w2[16];
  if (Wt) {
    const float2* wrow = (const float2*)(Wt + (size_t)j * NRES);
#pragma unroll
    for (int k = 0; k < 16; ++k) w2[k] = wrow[lane + 64 * k];
  } else {
#pragma unroll
    for (int k = 0; k < 16; ++k) {
      w2[k].x = W[(size_t)(2 * lane + 128 * k) * NRES + j];
      w2[k].y = W[(size_t)(2 * lane + 128 * k + 1) * NRES + j];
    }
  }

  float vold = 0.f;  // v_{t-1}[j], live on lane==0 of each wave
#pragma unroll
  for (int q = 0; q < 4; ++q) v_lds[0][tid + 512 * q] = 0.f;
  __syncthreads();

  for (int t = 0; t < T; ++t) {
    const int buf = t & 1;
    const size_t idx = (size_t)t * NRES + j;
    float u = (lane == 0) ? UY[idx] : 0.f;  // in flight during the poll

    if (t > 0) {
      u64* src = vtag + (size_t)((t - 1) & (RBUF - 1)) * NRES;
      unsigned done = 0;
      while (done != 0xFu) {
        u64 w[4];
#pragma unroll
        for (int q = 0; q < 4; ++q)
          w[q] = __hip_atomic_load(&src[tid + 512 * q], __ATOMIC_RELAXED,
                                   __HIP_MEMORY_SCOPE_AGENT);
#pragma unroll
        for (int q = 0; q < 4; ++q) {
          if (!(done & (1u << q)) && (u32)(w[q] >> 32) == (u32)t) {
            v_lds[buf][tid + 512 * q] = __uint_as_float((u32)w[q]);
            done |= 1u << q;
          }
        }
      }
      __syncthreads();
    }

    // dot(v, W[:,j]) : 16 x float2/lane, 2-way LDS aliasing (free), 2 chains
    float acc0 = 0.f, acc1 = 0.f;
#pragma unroll
    for (int k = 0; k < 16; k += 2) {
      float2 va = *(const float2*)&v_lds[buf][2 * lane + 128 * k];
      float2 vb = *(const float2*)&v_lds[buf][2 * lane + 128 * (k + 1)];
      acc0 += w2[k].x * va.x + w2[k].y * va.y;
      acc1 += w2[k + 1].x * vb.x + w2[k + 1].y * vb.y;
    }
    float acc = acc0 + acc1;
    // butterfly reduce across the full 64-lane wave
#pragma unroll
    for (int off = 32; off >= 1; off >>= 1) acc += __shfl_xor(acc, off);

    if (lane == 0) {
      float xx = acc + u;
      float e = __expf(2.f * xx);        // v_exp_f32 path
      float th = 1.f - 2.f / (e + 1.f);  // == tanh(xx) exactly
      float vnew = 0.5f * vold + 0.5f * th;
      vold = vnew;
      UY[idx] = vnew;  // states[t][j]
      u64 w = ((u64)(u32)(t + 1) << 32) | (u64)__float_as_uint(vnew);
      (void)__hip_atomic_exchange(&vtag[(size_t)(t & (RBUF - 1)) * NRES + j],
                                  w, __ATOMIC_RELAXED,
                                  __HIP_MEMORY_SCOPE_AGENT);
    }
  }
}

extern "C" void kernel_launch(void* const* d_in, const int* in_sizes, int n_in,
                              void* d_out, int out_size, void* d_ws, size_t ws_size,
                              hipStream_t stream) {
  const float* x   = (const float*)d_in[0];
  const float* Win = (const float*)d_in[1];
  const float* W   = (const float*)d_in[2];
  float* U = (float*)d_out;

  const int T = out_size / NRES;  // 4096
  const int K = in_sizes[0] / T;  // 4096 (nInput)

  char* ws = (char*)d_ws;
  u64* vtag = (u64*)ws;  // [RBUF][NRES] = 64 KB @ 0
  const size_t vtag_bytes = (size_t)RBUF * NRES * sizeof(u64);
  float* Wt = nullptr;
  if (ws_size >= (1u << 20) + (size_t)NRES * NRES * sizeof(float))
    Wt = (float*)(ws + (1u << 20));  // 16 MB @ 1 MB

  // tags must be zeroed every launch (replays would otherwise see stale epochs)
  hipMemsetAsync(vtag, 0, vtag_bytes, stream);

  if (Wt) transpose_k<<<dim3(NRES / 32, NRES / 32), dim3(32, 8), 0, stream>>>(W, Wt);

  gemm_uproj<<<dim3(NRES / 128, T / 128), 256, 0, stream>>>(x, Win, U, T, NRES, K);

  void* args[] = {(void*)&Wt, (void*)&W, (void*)&vtag, (void*)&U, (void*)&T};
  hipLaunchCooperativeKernel((const void*)esn_scan, dim3(NBLK), dim3(512), args,
                             0, stream);
}